// Round 12
// baseline (156.456 us; speedup 1.0000x reference)
//
#include <hip/hip_runtime.h>
#include <hip/hip_fp16.h>

// AxialAttention on MI355X (gfx950).
// x: [8,128,128,128] fp32, attend along H. Problem = (n0,h,w): S=128, d=16.
// K1 (attn): fully-MFMA, round-5 geometry (measured best: 46us).
//   Block = 512 thr / 8 waves owns an 8-w stripe of one (n0,h); wp-sibling
//   blocks (delta-bb=8) land on the same XCD and consume the other half of
//   each 64B x line from L2. x staged to LDS as f16 (40KB -> 4 blocks/CU).
//   Fragment chain (D==A/B layout identity of 16x16x16 MFMA):
//     Q^T = mfma(Wq, y^T) (scaled by 1/sqrt(128)*log2e), K^T = mfma(Wk, y^T),
//     V = mfma(y, Wv^T), P^T = exp2(mfma(K, Q)) via cvt_pkrtz, O = mfma(P, V).
//   NO setprio: round-11 A/B showed it regresses attn 50->57us (waves are
//   phase-lockstep within a block -> m190-null regime, not m191).
//   AO epilogue packs via v_cvt_pk_bf16_f32 (RNE). AO bf16 [b=(n0,w)][s][c].
//   Wo->bf16 prep folded (16 elem/block). __launch_bounds__(512,4): VGPR cap
//   128 (cap 64 = round-6 spill disaster).
// K2 (proj): block=(n0,s,w-half). TRANSPOSED mapping vs rounds 4-11:
//   A=AO (m=w), B=Wo (n=e) -> D rows are w, consecutive per acc register ->
//   float4 stores (8 wide stores/lane instead of 32 scalar: round-11 proj's
//   epilogue was 32 scalar stores with 4 scattered 64B chunks/instr).
//   Wo B-frags preloaded to regs, AO half-tile staged to LDS (batched loads),
//   4 waves x (32e x 64w) 16x16x32 bf16 MFMA. Bit-identical accumulation.

typedef __attribute__((ext_vector_type(4))) float f32x4;
typedef __attribute__((ext_vector_type(4))) _Float16 f16x4;
typedef __attribute__((ext_vector_type(2))) __fp16 fp16x2r;  // cvt_pkrtz native type
typedef __attribute__((ext_vector_type(8))) short bf16x8;

__device__ __forceinline__ unsigned int bf16_rne(float x) {
    unsigned int u = __float_as_uint(x);
    return (u + 0x7fffu + ((u >> 16) & 1u)) >> 16;
}
__device__ __forceinline__ unsigned int pack_half2(float a, float b) {
    __half2 h = __floats2half2_rn(a, b);
    return *reinterpret_cast<unsigned int*>(&h);
}

__global__ __launch_bounds__(512, 4) void axattn_attn(
    const float* __restrict__ x,
    const float* __restrict__ Wq,
    const float* __restrict__ Wk,
    const float* __restrict__ Wv,
    const float* __restrict__ Wo,
    unsigned short* __restrict__ Wob,
    unsigned short* __restrict__ AO)   // bf16 [(n0*128+w)][s][c]
{
    // bb = ((n0*8+h)*2 + wp)*8 + xcd ; w0 = xcd*16 + wp*8 ; wave wvi: w = w0+wvi
    // wp-sibling blocks (bb, bb+8) land on the same XCD -> share x cache lines.
    int bb  = blockIdx.x;
    int xcd = bb & 7;
    int k   = bb >> 3;         // (n0*8+h)*2 + wp
    int wp  = k & 1;
    int nh  = k >> 1;          // n0*8 + h
    int n0  = nh >> 3;
    int h   = nh & 7;
    int tid = threadIdx.x;
    int wvi = tid >> 6;        // wave 0..7 -> own problem (w)
    int l   = tid & 63;
    int lr  = l & 15;          // fragment row/col index
    int lg  = l >> 4;          // fragment k-group
    int w0  = xcd * 16 + wp * 8;
    int w   = w0 + wvi;

    // folded prep: Wo fp32 -> bf16 (1024 blocks x 16 = 16384 elements)
    if (tid < 16) {
        int i = bb * 16 + tid;
        Wob[i] = (unsigned short)bf16_rne(Wo[i]);
    }

    // x-tile as f16: [w-local 0..7][row][c2] ; row stride 10 u32 (40B)
    __shared__ unsigned int xs[8 * 1280];   // 40 KB

    // Staging: tid -> (q = w-quad 0/1, row, c2b); 4 c2 per thread.
    // Per wave-instr: lane pairs (q=0,1) cover 32B contiguous; 32 rows.
    {
        int q   = tid & 1;
        int row = (tid >> 1) & 127;
        int c2b = tid >> 8;    // 0/1
        const float* gp0 = x + ((size_t)(n0 * 128 + h * 16) * 128 + row) * 128 + w0 + q * 4;
        float4 va[4], vb[4];
        #pragma unroll
        for (int it = 0; it < 4; ++it) {
            const float* gp = gp0 + (size_t)(2 * (it * 2 + c2b)) * 16384;
            va[it] = *(const float4*)gp;            // c = 2*c2
            vb[it] = *(const float4*)(gp + 16384);  // c = 2*c2+1
        }
        #pragma unroll
        for (int it = 0; it < 4; ++it) {
            int c2 = it * 2 + c2b;
            unsigned int* dp = xs + (q * 4) * 1280 + row * 10 + c2;
            dp[0]    = pack_half2(va[it].x, vb[it].x);
            dp[1280] = pack_half2(va[it].y, vb[it].y);
            dp[2560] = pack_half2(va[it].z, vb[it].z);
            dp[3840] = pack_half2(va[it].w, vb[it].w);
        }
    }

    const float qsc = 0.088388347648318447f * 1.4426950408889634f; // 1/sqrt(128)*log2e
    const f32x4 zf = {0.f, 0.f, 0.f, 0.f};

    // Weight fragments: lane reads W[lr][lg*4 .. +3] (overlaps staging).
    float4 wqf = *(const float4*)(Wq + lr * 16 + lg * 4);
    float4 wkf = *(const float4*)(Wk + lr * 16 + lg * 4);
    float4 wvf = *(const float4*)(Wv + lr * 16 + lg * 4);
    f16x4 fq = {(_Float16)wqf.x, (_Float16)wqf.y, (_Float16)wqf.z, (_Float16)wqf.w};
    f16x4 fk = {(_Float16)wkf.x, (_Float16)wkf.y, (_Float16)wkf.z, (_Float16)wkf.w};
    f16x4 fv = {(_Float16)wvf.x, (_Float16)wvf.y, (_Float16)wvf.z, (_Float16)wvf.w};

    __syncthreads();

    // y fragments from LDS: yf[rt][j] = y[rt*16+lr][lg*4+j]
    const char* yb = (const char*)xs + wvi * 5120 + lr * 40 + lg * 8;
    f16x4 yf[8];
    #pragma unroll
    for (int rt = 0; rt < 8; ++rt)
        yf[rt] = *(const f16x4*)(yb + rt * 640);   // 16 rows * 40B

    // Projections: per 16-row tile t.
    f16x4 qb[8], ka[8], vb[8];
    #pragma unroll
    for (int t = 0; t < 8; ++t) {
        f32x4 qt = __builtin_amdgcn_mfma_f32_16x16x16f16(fq, yf[t], zf, 0, 0, 0);
        f32x4 kt = __builtin_amdgcn_mfma_f32_16x16x16f16(fk, yf[t], zf, 0, 0, 0);
        f32x4 vt = __builtin_amdgcn_mfma_f32_16x16x16f16(yf[t], fv, zf, 0, 0, 0);
        qb[t] = (f16x4){(_Float16)(qt[0] * qsc), (_Float16)(qt[1] * qsc),
                        (_Float16)(qt[2] * qsc), (_Float16)(qt[3] * qsc)};
        ka[t] = (f16x4){(_Float16)kt[0], (_Float16)kt[1], (_Float16)kt[2], (_Float16)kt[3]};
        vb[t] = (f16x4){(_Float16)vt[0], (_Float16)vt[1], (_Float16)vt[2], (_Float16)vt[3]};
    }

    // AO base for this lane: row q = qt*16 + lg*4 + r, col c = h*16 + lr.
    unsigned short* aob = AO + ((size_t)(n0 * 128 + w) * 128 + lg * 4) * 128 + h * 16 + lr;

    #pragma unroll
    for (int qt = 0; qt < 8; ++qt) {
        f32x4 s[8];
        #pragma unroll
        for (int kt = 0; kt < 8; ++kt)
            s[kt] = __builtin_amdgcn_mfma_f32_16x16x16f16(ka[kt], qb[qt], zf, 0, 0, 0);
        float sum = 0.f;
        f16x4 pa[8];
        #pragma unroll
        for (int kt = 0; kt < 8; ++kt) {
            float p0 = __builtin_amdgcn_exp2f(s[kt][0]);
            float p1 = __builtin_amdgcn_exp2f(s[kt][1]);
            float p2 = __builtin_amdgcn_exp2f(s[kt][2]);
            float p3 = __builtin_amdgcn_exp2f(s[kt][3]);
            sum += (p0 + p1) + (p2 + p3);
            union { fp16x2r h2[2]; f16x4 h4; } up;
            up.h2[0] = __builtin_amdgcn_cvt_pkrtz(p0, p1);
            up.h2[1] = __builtin_amdgcn_cvt_pkrtz(p2, p3);
            pa[kt] = up.h4;
        }
        sum += __shfl_xor(sum, 16);
        sum += __shfl_xor(sum, 32);
        // PV as two independent 4-deep chains (halves serial MFMA latency)
        f32x4 oA = zf, oB = zf;
        #pragma unroll
        for (int kt = 0; kt < 4; ++kt) {
            oA = __builtin_amdgcn_mfma_f32_16x16x16f16(pa[kt],     vb[kt],     oA, 0, 0, 0);
            oB = __builtin_amdgcn_mfma_f32_16x16x16f16(pa[kt + 4], vb[kt + 4], oB, 0, 0, 0);
        }
        f32x4 o = oA + oB;
        float rl = 1.f / sum;      // valid for q-column lr
        #pragma unroll
        for (int rp = 0; rp < 2; ++rp) {           // row pairs (RNE == bf16_rne)
            float rs0 = __shfl(rl, lg * 4 + 2 * rp);
            float rs1 = __shfl(rl, lg * 4 + 2 * rp + 1);
            float v0 = o[2 * rp] * rs0;
            float v1 = o[2 * rp + 1] * rs1;
            unsigned int u;
            asm("v_cvt_pk_bf16_f32 %0, %1, %2" : "=v"(u) : "v"(v0), "v"(v1));
            aob[((size_t)qt * 16 + 2 * rp) * 128]     = (unsigned short)u;
            aob[((size_t)qt * 16 + 2 * rp + 1) * 128] = (unsigned short)(u >> 16);
        }
    }
}

// MFMA out-proj v4 (transposed mapping: m=w, n=e -> float4 stores).
// Block = (n0, s, w-half); Wo B-frags preloaded to regs, AO half-tile staged
// to LDS; 4 waves, wave wv: e-tile [wv*32,+32) x 64 w.
__global__ __launch_bounds__(256) void axattn_proj(
    const unsigned short* __restrict__ AOb,
    const unsigned short* __restrict__ Wob,
    const float* __restrict__ bo,
    float* __restrict__ out)
{
    int bb  = blockIdx.x;
    int wh  = bb & 1;
    int s   = (bb >> 1) & 127;
    int n0  = bb >> 8;
    int tid = threadIdx.x;
    int wv  = tid >> 6;
    int l   = tid & 63;
    int lr  = l & 15;
    int lg  = l >> 4;
    int lk  = lg * 8;
    int eb  = wv * 32;

    // AO half-tile [w-row 0..63][c 0..127] bf16, row stride 272B (256 + 16 pad)
    __shared__ char as_[64 * 272];

    // B-frags (Wo, n=e): lane lr -> e row; global loads overlap staging below.
    const unsigned short* wp_ = Wob + (size_t)(eb + lr) * 128 + lk;
    bf16x8 wo0[4], wo1[4];
    #pragma unroll
    for (int ct = 0; ct < 4; ++ct) {
        wo0[ct] = *(const bf16x8*)(wp_ + ct * 32);
        wo1[ct] = *(const bf16x8*)(wp_ + 16 * 128 + ct * 32);
    }

    // Batched staging: all 4 uint4 loads in flight before LDS stores.
    {
        uint4 t4[4];
        #pragma unroll
        for (int it = 0; it < 4; ++it) {
            int flat = it * 256 + tid;     // 0..1023
            int row  = flat >> 4;          // 0..63
            int seg  = flat & 15;
            t4[it] = *((const uint4*)(AOb
                + ((size_t)(n0 * 128 + wh * 64 + row) * 128 + s) * 128) + seg);
        }
        #pragma unroll
        for (int it = 0; it < 4; ++it) {
            int flat = it * 256 + tid;
            int row  = flat >> 4;
            int seg  = flat & 15;
            *(uint4*)(as_ + row * 272 + seg * 16) = t4[it];
        }
    }
    __syncthreads();

    f32x4 acc[4][2];   // [mi over w][ni over e]
    #pragma unroll
    for (int mi = 0; mi < 4; ++mi)
        #pragma unroll
        for (int ni = 0; ni < 2; ++ni)
            acc[mi][ni] = (f32x4){0.f, 0.f, 0.f, 0.f};

    #pragma unroll
    for (int ct = 0; ct < 4; ++ct) {             // k = c tile of 32
        #pragma unroll
        for (int mi = 0; mi < 4; ++mi) {
            bf16x8 a = *(const bf16x8*)(as_ + (mi * 16 + lr) * 272 + (lk + ct * 32) * 2);
            acc[mi][0] = __builtin_amdgcn_mfma_f32_16x16x32_bf16(a, wo0[ct], acc[mi][0], 0, 0, 0);
            acc[mi][1] = __builtin_amdgcn_mfma_f32_16x16x32_bf16(a, wo1[ct], acc[mi][1], 0, 0, 0);
        }
    }

    // Store: lane holds e = eb + ni*16 + lr (col), w = wh*64 + mi*16 + lg*4 + r
    // (rows, consecutive in r) -> one float4 per (mi,ni); lanes tile 16 e-rows
    // x 64B fully-used contiguous chunks.
    #pragma unroll
    for (int ni = 0; ni < 2; ++ni) {
        int e = eb + ni * 16 + lr;
        float bv = bo[e];
        float* obase = out + ((size_t)(n0 * 128 + e) * 128 + s) * 128 + wh * 64 + lg * 4;
        #pragma unroll
        for (int mi = 0; mi < 4; ++mi) {
            float4 v = make_float4(acc[mi][ni][0] + bv, acc[mi][ni][1] + bv,
                                   acc[mi][ni][2] + bv, acc[mi][ni][3] + bv);
            *(float4*)(obase + mi * 16) = v;
        }
    }
}

extern "C" void kernel_launch(void* const* d_in, const int* in_sizes, int n_in,
                              void* d_out, int out_size, void* d_ws, size_t ws_size,
                              hipStream_t stream) {
    const float* x  = (const float*)d_in[0];
    const float* Wq = (const float*)d_in[1];
    const float* Wk = (const float*)d_in[2];
    const float* Wv = (const float*)d_in[3];
    const float* Wo = (const float*)d_in[4];
    const float* bo = (const float*)d_in[5];
    float* out = (float*)d_out;

    unsigned short* AOb = (unsigned short*)d_ws;                        // 32 MiB bf16
    unsigned short* Wob = (unsigned short*)((char*)d_ws + (32u << 20)); // 32 KiB bf16

    axattn_attn<<<1024, 512, 0, stream>>>(x, Wq, Wk, Wv, Wo, Wob, AOb);
    axattn_proj<<<2048, 256, 0, stream>>>(AOb, Wob, bo, out);
}